// Round 6
// baseline (323.749 us; speedup 1.0000x reference)
//
#include <hip/hip_runtime.h>
#include <stdint.h>

#define NBLOCKS 256
#define WPB 16                        // waves per block (1024 threads)
#define SLOTS (NBLOCKS * WPB)         // 4096 independent wave slots
#define SMEM_BYTES (131072 + 1024 + 1024 + 2048)  // B-frags + b1s + w2s + w-slices

typedef __attribute__((ext_vector_type(8))) short bfrag_t;
typedef __attribute__((ext_vector_type(4))) float f32x4;

static __device__ __forceinline__ unsigned short f2bf(float f) {
  unsigned int u = __float_as_uint(f);
  u += 0x7fffu + ((u >> 16) & 1u);   // RNE
  return (unsigned short)(u >> 16);
}

static __device__ __forceinline__ float tanh_fast(float s) {
  // tanh(s) = 1 - 2/(1+e^{2s}); saturates at +-1, no clamp needed
  float e = __builtin_exp2f(s * 2.8853900817779268f);
  float r = __builtin_amdgcn_rcpf(1.f + e);
  return __builtin_fmaf(-2.f, r, 1.f);
}

static __device__ __forceinline__ bfrag_t pack8(f32x4 a, f32x4 b) {
  union { bfrag_t v; unsigned int u[4]; } r;
  asm("v_cvt_pk_bf16_f32 %0, %1, %2" : "=v"(r.u[0]) : "v"(a[0]), "v"(a[1]));
  asm("v_cvt_pk_bf16_f32 %0, %1, %2" : "=v"(r.u[1]) : "v"(a[2]), "v"(a[3]));
  asm("v_cvt_pk_bf16_f32 %0, %1, %2" : "=v"(r.u[2]) : "v"(b[0]), "v"(b[1]));
  asm("v_cvt_pk_bf16_f32 %0, %1, %2" : "=v"(r.u[3]) : "v"(b[2]), "v"(b[3]));
  return r.v;
}

#define KEEPA(A) asm volatile("" : "+v"(A[0]), "+v"(A[1]), "+v"(A[2]), "+v"(A[3]), \
                                    "+v"(A[4]), "+v"(A[5]), "+v"(A[6]), "+v"(A[7]))

#define GLD16(gp, lp) __builtin_amdgcn_global_load_lds( \
    (const __attribute__((address_space(1))) void*)(gp), \
    (__attribute__((address_space(3))) void*)(lp), 16, 0, 0)

// Pre-swizzle W1 (f32 [256][256], k-major) into MFMA B-fragment order, bf16.
// W1f[((cc*8+kk)*64 + lane)*8 + j] = bf16(W1[kk*32 + 8*(lane>>4) + j][cc*16 + (lane&15)])
__global__ void prep_w1_kernel(const float* __restrict__ W1, unsigned short* __restrict__ W1f) {
  const int bx = blockIdx.x;   // cc*8 + kk, 0..127
  const int l = threadIdx.x;   // 0..63
  const int cc = bx >> 3, kk = bx & 7;
  const int h = cc * 16 + (l & 15);
  const int kbase = kk * 32 + ((l >> 4) << 3);
  bfrag_t pk;
#pragma unroll
  for (int j = 0; j < 8; ++j) pk[j] = (short)f2bf(W1[(size_t)(kbase + j) * 256 + h]);
  *(bfrag_t*)(W1f + (size_t)(bx * 64 + l) * 8) = pk;
}

__launch_bounds__(1024, 4)
__global__ void attnpool_kernel(const float* __restrict__ x,
                                const int* __restrict__ batch,
                                const unsigned short* __restrict__ W1f,
                                const float* __restrict__ b1,
                                const float* __restrict__ W2,
                                const float* __restrict__ b2,
                                float* __restrict__ out,   // raw weighted sums (zeroed)
                                float* __restrict__ Zp,    // softmax denominator (zeroed)
                                int N, int ntiles, int tps) {
  extern __shared__ char smem[];
  char*  Bl  = smem;                       // [128 frags][64 lanes][16B], frag-linear
  float* b1s = (float*)(smem + 131072);    // [256]
  float* w2s = (float*)(smem + 132096);    // [256]
  float* wsl = (float*)(smem + 133120);    // [16 waves][32] per-wave w slices

  const int t = threadIdx.x;
  const int lane = t & 63;
  const int wv = t >> 6;
  const int l15 = lane & 15;
  const int hi = lane >> 4;

  // ---- prologue: stage W1f (frag-linear) + b1/W2 into LDS; ONE barrier ----
#pragma unroll
  for (int i = 0; i < 8; ++i) {
    const int f = wv * 8 + i;
    const unsigned short* src = W1f + (size_t)f * 512 + lane * 8;
    GLD16(src, Bl + f * 1024);
  }
  if (t < 256) { b1s[t] = b1[t]; w2s[t] = W2[t]; }
  __syncthreads();   // only barrier in the kernel

  const float b2c = b2[0];
  const int slot = blockIdx.x * WPB + wv;
  const int t0 = slot * tps;
  const int t1 = min(t0 + tps, ntiles);

  float zacc = 0.f;
  float pacc[16];    // quad-partial col sums: i=(kk*2+par), col=kk*32+hi*8+2*(l15&3)+par
#pragma unroll
  for (int i = 0; i < 16; ++i) pacc[i] = 0.f;
  int gcur = -1;
  const char* bwave = Bl + lane * 16;
  float* ws = wsl + (wv << 5);

  bfrag_t A0[8], A1[8];

  // flush: reduce pacc over the 4 l15-quads, atomics from lanes l15<4
  auto flush = [&]() {
#pragma unroll
    for (int i = 0; i < 16; ++i) {
      pacc[i] += __shfl_xor(pacc[i], 4);
      pacc[i] += __shfl_xor(pacc[i], 8);
    }
    if (l15 < 4) {
      float* po = out + (size_t)gcur * 256 + hi * 8 + 2 * l15;
#pragma unroll
      for (int i = 0; i < 16; ++i)
        atomicAdd(po + (i >> 1) * 32 + (i & 1), pacc[i]);
    }
#pragma unroll
    for (int i = 0; i < 16; ++i) pacc[i] = 0.f;
  };

  // pool_pass: unpack A-frags, weight, 2-step butterfly over l15, select q=l15&3
  auto pool_pass = [&](float m0, float m1) {
    const bool s0 = (l15 & 1) != 0, s1 = (l15 & 2) != 0;
#pragma unroll
    for (int half = 0; half < 2; ++half) {
      float part[4][4][2];
#pragma unroll
      for (int k2 = 0; k2 < 4; ++k2) {
        const int kk = half * 4 + k2;
        union { bfrag_t v; unsigned int u[4]; } ua, ub;
        ua.v = A0[kk]; ub.v = A1[kk];
#pragma unroll
        for (int q = 0; q < 4; ++q) {
          const float alo = __uint_as_float(ua.u[q] << 16);
          const float ahi = __uint_as_float(ua.u[q] & 0xffff0000u);
          const float blo = __uint_as_float(ub.u[q] << 16);
          const float bhi = __uint_as_float(ub.u[q] & 0xffff0000u);
          part[k2][q][0] = __builtin_fmaf(m0, alo, m1 * blo);
          part[k2][q][1] = __builtin_fmaf(m0, ahi, m1 * bhi);
        }
      }
#pragma unroll
      for (int k2 = 0; k2 < 4; ++k2)
#pragma unroll
        for (int q = 0; q < 4; ++q)
#pragma unroll
          for (int p = 0; p < 2; ++p) {
            float v = part[k2][q][p];
            v += __shfl_xor(v, 1);
            v += __shfl_xor(v, 2);
            part[k2][q][p] = v;
          }
#pragma unroll
      for (int k2 = 0; k2 < 4; ++k2)
#pragma unroll
        for (int p = 0; p < 2; ++p) {
          const float v01 = s0 ? part[k2][1][p] : part[k2][0][p];
          const float v23 = s0 ? part[k2][3][p] : part[k2][2][p];
          pacc[(half * 4 + k2) * 2 + p] += s1 ? v23 : v01;
        }
    }
  };

  for (int tile = t0; tile < t1; ++tile) {
    const int R0 = tile * 32;

    // batch ids: lane r (r = lane&31) holds batch[R0+r]
    int bid;
    {
      const int rg = min(R0 + (lane & 31), N - 1);
      bid = batch[rg];
    }

    // ---- A-frags: global f32 -> bf16 regs (rows l15 and 16+l15) ----
    {
      const int r0g = min(R0 + l15, N - 1);
      const int r1g = min(R0 + 16 + l15, N - 1);
      const float* p0 = x + (size_t)r0g * 256 + hi * 8;
      const float* p1 = x + (size_t)r1g * 256 + hi * 8;
#pragma unroll
      for (int kk = 0; kk < 8; ++kk) {
        const f32x4 u0 = *(const f32x4*)(p0 + kk * 32);
        const f32x4 u1 = *(const f32x4*)(p0 + kk * 32 + 4);
        const f32x4 v0 = *(const f32x4*)(p1 + kk * 32);
        const f32x4 v1 = *(const f32x4*)(p1 + kk * 32 + 4);
        A0[kk] = pack8(u0, u1);
        A1[kk] = pack8(v0, v1);
      }
    }

    // ---- score: cc-outer MFMA, B from LDS (conflict-free lane-linear) ----
    float s0v[4] = {0.f, 0.f, 0.f, 0.f};
    float s1v[4] = {0.f, 0.f, 0.f, 0.f};
#pragma unroll 2
    for (int cc = 0; cc < 16; ++cc) {
      KEEPA(A0);  // pin A in VGPRs across the loop
      KEEPA(A1);
      const char* bb = bwave + cc * 8192;
      f32x4 acc0 = {0.f, 0.f, 0.f, 0.f}, acc1 = {0.f, 0.f, 0.f, 0.f};
#pragma unroll
      for (int kk = 0; kk < 8; ++kk) {
        const bfrag_t Bk = *(const bfrag_t*)(bb + kk * 1024);
        acc0 = __builtin_amdgcn_mfma_f32_16x16x32_bf16(A0[kk], Bk, acc0, 0, 0, 0);
        acc1 = __builtin_amdgcn_mfma_f32_16x16x32_bf16(A1[kk], Bk, acc1, 0, 0, 0);
      }
      const float b1c = b1s[cc * 16 + l15];
      const float w2c = w2s[cc * 16 + l15];
#pragma unroll
      for (int r = 0; r < 4; ++r) {
        s0v[r] += tanh_fast(acc0[r] + b1c) * w2c;
        s1v[r] += tanh_fast(acc1[r] + b1c) * w2c;
      }
    }

    // ---- reduce over 16-lane col groups; w = exp(score + b2) ----
    f32x4 w0v, w1v;
#pragma unroll
    for (int r = 0; r < 4; ++r) {
      float v0 = s0v[r], v1 = s1v[r];
      v0 += __shfl_xor(v0, 1); v0 += __shfl_xor(v0, 2);
      v0 += __shfl_xor(v0, 4); v0 += __shfl_xor(v0, 8);
      v1 += __shfl_xor(v1, 1); v1 += __shfl_xor(v1, 2);
      v1 += __shfl_xor(v1, 4); v1 += __shfl_xor(v1, 8);
      w0v[r] = (R0 + hi * 4 + r < N) ? __expf(v0 + b2c) : 0.f;
      w1v[r] = (R0 + 16 + hi * 4 + r < N) ? __expf(v1 + b2c) : 0.f;
    }
    // Z partial: rows unique per (hi,r); reduce across hi
    {
      float z = w0v[0] + w0v[1] + w0v[2] + w0v[3] + w1v[0] + w1v[1] + w1v[2] + w1v[3];
      z += __shfl_xor(z, 16);
      z += __shfl_xor(z, 32);
      zacc += z;
    }

    // ---- broadcast w by row via per-wave LDS slice (no barrier: same wave) ----
    if (l15 == 0) {
      *(f32x4*)(ws + hi * 4) = w0v;        // rows hi*4+r
      *(f32x4*)(ws + 16 + hi * 4) = w1v;   // rows 16+hi*4+r
    }
    const float w0f = ws[l15];         // weight of row l15
    const float w1f = ws[l15 + 16];    // weight of row 16+l15

    // ---- segmented pooling straight from the bf16 registers ----
    const int g_first = __builtin_amdgcn_readlane(bid, 0);
    const int g_last  = __builtin_amdgcn_readlane(bid, 31);
    if (g_first == g_last) {
      if (g_first != gcur) { if (gcur >= 0) flush(); gcur = g_first; }
      pool_pass(w0f, w1f);
    } else {
      int s = 0;
      while (s < 32) {
        const int g = __builtin_amdgcn_readlane(bid, s);
        int e = s + 1;
        while (e < 32 && __builtin_amdgcn_readlane(bid, e) == g) ++e;
        if (g != gcur) { if (gcur >= 0) flush(); gcur = g; }
        const float m0 = (l15 >= s && l15 < e) ? w0f : 0.f;
        const float m1 = (16 + l15 >= s && 16 + l15 < e) ? w1f : 0.f;
        pool_pass(m0, m1);
        s = e;
      }
    }
  }

  if (gcur >= 0) flush();
  if (lane == 0 && zacc != 0.f) atomicAdd(Zp, zacc);
}

__global__ void finalize_kernel(float* __restrict__ out, const float* __restrict__ Zp, int n4) {
  const int i = blockIdx.x * blockDim.x + threadIdx.x;
  if (i < n4) {
    const float zi = 1.f / Zp[0];
    f32x4* p = (f32x4*)out;
    f32x4 v = p[i];
    v[0] *= zi; v[1] *= zi; v[2] *= zi; v[3] *= zi;
    p[i] = v;
  }
}

extern "C" void kernel_launch(void* const* d_in, const int* in_sizes, int n_in,
                              void* d_out, int out_size, void* d_ws, size_t ws_size,
                              hipStream_t stream) {
  const float* x  = (const float*)d_in[0];
  const int* batch = (const int*)d_in[1];
  const float* W1 = (const float*)d_in[2];
  const float* b1 = (const float*)d_in[3];
  const float* W2 = (const float*)d_in[4];
  const float* b2 = (const float*)d_in[5];
  float* out = (float*)d_out;
  const int N = in_sizes[1];

  unsigned short* W1f = (unsigned short*)d_ws;          // 128 KB
  float* Zp = (float*)((char*)d_ws + 131072);           // 4 B

  static int attr_done = 0;  // host-side only; idempotent attribute, not kernel state
  if (!attr_done) {
    hipFuncSetAttribute((const void*)attnpool_kernel,
                        hipFuncAttributeMaxDynamicSharedMemorySize, SMEM_BYTES);
    attr_done = 1;
  }

  const int ntiles = (N + 31) / 32;
  const int tps = (ntiles + SLOTS - 1) / SLOTS;

  hipMemsetAsync(d_out, 0, (size_t)out_size * sizeof(float), stream);
  hipMemsetAsync(Zp, 0, sizeof(float), stream);
  prep_w1_kernel<<<128, 64, 0, stream>>>(W1, W1f);
  attnpool_kernel<<<NBLOCKS, 1024, SMEM_BYTES, stream>>>(x, batch, W1f, b1, W2, b2,
                                                         out, Zp, N, ntiles, tps);
  finalize_kernel<<<(out_size / 4 + 255) / 256, 256, 0, stream>>>(out, Zp, out_size / 4);
}

// Round 8
// 309.957 us; speedup vs baseline: 1.0445x; 1.0445x over previous
//
#include <hip/hip_runtime.h>
#include <stdint.h>

#define NBLOCKS 256
#define WPB 16                        // waves per block (1024 threads)
#define SLOTS (NBLOCKS * WPB)         // 4096 independent wave slots
#define SMEM_BYTES (131072 + 1024 + 1024 + 2048)  // B-frags + b1s + w2s + w-slices

typedef __attribute__((ext_vector_type(8))) short bfrag_t;
typedef __attribute__((ext_vector_type(4))) float f32x4;

static __device__ __forceinline__ unsigned short f2bf(float f) {
  unsigned int u = __float_as_uint(f);
  u += 0x7fffu + ((u >> 16) & 1u);   // RNE
  return (unsigned short)(u >> 16);
}

static __device__ __forceinline__ float tanh_fast(float s) {
  // tanh(s) = 1 - 2/(1+e^{2s}); saturates at +-1, no clamp needed
  float e = __builtin_exp2f(s * 2.8853900817779268f);
  float r = __builtin_amdgcn_rcpf(1.f + e);
  return __builtin_fmaf(-2.f, r, 1.f);
}

static __device__ __forceinline__ bfrag_t pack8(f32x4 a, f32x4 b) {
  union { bfrag_t v; unsigned int u[4]; } r;
  asm("v_cvt_pk_bf16_f32 %0, %1, %2" : "=v"(r.u[0]) : "v"(a[0]), "v"(a[1]));
  asm("v_cvt_pk_bf16_f32 %0, %1, %2" : "=v"(r.u[1]) : "v"(a[2]), "v"(a[3]));
  asm("v_cvt_pk_bf16_f32 %0, %1, %2" : "=v"(r.u[2]) : "v"(b[0]), "v"(b[1]));
  asm("v_cvt_pk_bf16_f32 %0, %1, %2" : "=v"(r.u[3]) : "v"(b[2]), "v"(b[3]));
  return r.v;
}

#define KEEPA(A) asm volatile("" : "+v"(A[0]), "+v"(A[1]), "+v"(A[2]), "+v"(A[3]), \
                                    "+v"(A[4]), "+v"(A[5]), "+v"(A[6]), "+v"(A[7]))

#define GLD16(gp, lp) __builtin_amdgcn_global_load_lds( \
    (const __attribute__((address_space(1))) void*)(gp), \
    (__attribute__((address_space(3))) void*)(lp), 16, 0, 0)

// Pre-swizzle W1 (f32 [256][256], k-major) into MFMA B-fragment order, bf16.
// W1f[((cc*8+kk)*64 + lane)*8 + j] = bf16(W1[kk*32 + 8*(lane>>4) + j][cc*16 + (lane&15)])
__global__ void prep_w1_kernel(const float* __restrict__ W1, unsigned short* __restrict__ W1f) {
  const int bx = blockIdx.x;   // cc*8 + kk, 0..127
  const int l = threadIdx.x;   // 0..63
  const int cc = bx >> 3, kk = bx & 7;
  const int h = cc * 16 + (l & 15);
  const int kbase = kk * 32 + ((l >> 4) << 3);
  bfrag_t pk;
#pragma unroll
  for (int j = 0; j < 8; ++j) pk[j] = (short)f2bf(W1[(size_t)(kbase + j) * 256 + h]);
  *(bfrag_t*)(W1f + (size_t)(bx * 64 + l) * 8) = pk;
}

__attribute__((amdgpu_flat_work_group_size(1024, 1024), amdgpu_waves_per_eu(4, 4)))
__global__ void attnpool_kernel(const float* __restrict__ x,
                                const int* __restrict__ batch,
                                const unsigned short* __restrict__ W1f,
                                const float* __restrict__ b1,
                                const float* __restrict__ W2,
                                const float* __restrict__ b2,
                                float* __restrict__ out,   // raw weighted sums (zeroed)
                                float* __restrict__ Zp,    // softmax denominator (zeroed)
                                int N, int ntiles, int tps) {
  extern __shared__ char smem[];
  char*  Bl  = smem;                       // [128 frags][64 lanes][16B], frag-linear
  float* b1s = (float*)(smem + 131072);    // [256]
  float* w2s = (float*)(smem + 132096);    // [256]
  float* wsl = (float*)(smem + 133120);    // [16 waves][32] per-wave w slices

  const int t = threadIdx.x;
  const int lane = t & 63;
  const int wv = t >> 6;
  const int l15 = lane & 15;
  const int hi = lane >> 4;

  // ---- prologue: stage W1f (frag-linear) + b1/W2 into LDS; ONE barrier ----
#pragma unroll
  for (int i = 0; i < 8; ++i) {
    const int f = wv * 8 + i;
    const unsigned short* src = W1f + (size_t)f * 512 + lane * 8;
    GLD16(src, Bl + f * 1024);
  }
  if (t < 256) { b1s[t] = b1[t]; w2s[t] = W2[t]; }
  __syncthreads();   // only barrier in the kernel

  const float b2c = b2[0];
  const int slot = blockIdx.x * WPB + wv;
  const int t0 = slot * tps;
  const int t1 = min(t0 + tps, ntiles);

  float zacc = 0.f;
  float pacc[16];    // quad-partial col sums: i=(kk*2+par), col=kk*32+hi*8+2*(l15&3)+par
#pragma unroll
  for (int i = 0; i < 16; ++i) pacc[i] = 0.f;
  int gcur = -1;
  const char* bwave = Bl + lane * 16;
  float* ws = wsl + (wv << 5);

  bfrag_t A0[8], A1[8];

  // flush: reduce pacc over the 4 l15-quads, atomics from lanes l15<4
  auto flush = [&]() {
#pragma unroll
    for (int i = 0; i < 16; ++i) {
      pacc[i] += __shfl_xor(pacc[i], 4);
      pacc[i] += __shfl_xor(pacc[i], 8);
    }
    if (l15 < 4) {
      float* po = out + (size_t)gcur * 256 + hi * 8 + 2 * l15;
#pragma unroll
      for (int i = 0; i < 16; ++i)
        atomicAdd(po + (i >> 1) * 32 + (i & 1), pacc[i]);
    }
#pragma unroll
    for (int i = 0; i < 16; ++i) pacc[i] = 0.f;
  };

  // pool_pass: kk-local (small live window): unpack A-frags, weight,
  // 2-step butterfly over l15 bits 0-1, select quad-position, accumulate.
  auto pool_pass = [&](float m0, float m1) {
    const bool s0 = (l15 & 1) != 0, s1 = (l15 & 2) != 0;
#pragma unroll
    for (int kk = 0; kk < 8; ++kk) {
      union { bfrag_t v; unsigned int u[4]; } ua, ub;
      ua.v = A0[kk]; ub.v = A1[kk];
      float part[4][2];
#pragma unroll
      for (int q = 0; q < 4; ++q) {
        const float alo = __uint_as_float(ua.u[q] << 16);
        const float ahi = __uint_as_float(ua.u[q] & 0xffff0000u);
        const float blo = __uint_as_float(ub.u[q] << 16);
        const float bhi = __uint_as_float(ub.u[q] & 0xffff0000u);
        part[q][0] = __builtin_fmaf(m0, alo, m1 * blo);
        part[q][1] = __builtin_fmaf(m0, ahi, m1 * bhi);
      }
#pragma unroll
      for (int q = 0; q < 4; ++q)
#pragma unroll
        for (int p = 0; p < 2; ++p) {
          float v = part[q][p];
          v += __shfl_xor(v, 1);
          v += __shfl_xor(v, 2);
          part[q][p] = v;
        }
#pragma unroll
      for (int p = 0; p < 2; ++p) {
        const float v01 = s0 ? part[1][p] : part[0][p];
        const float v23 = s0 ? part[3][p] : part[2][p];
        pacc[kk * 2 + p] += s1 ? v23 : v01;
      }
    }
  };

  for (int tile = t0; tile < t1; ++tile) {
    const int R0 = tile * 32;

    // batch ids: lane r (r = lane&31) holds batch[R0+r]
    int bid;
    {
      const int rg = min(R0 + (lane & 31), N - 1);
      bid = batch[rg];
    }

    // ---- A-frags: global f32 -> bf16 regs (rows l15 and 16+l15) ----
    {
      const int r0g = min(R0 + l15, N - 1);
      const int r1g = min(R0 + 16 + l15, N - 1);
      const float* p0 = x + (size_t)r0g * 256 + hi * 8;
      const float* p1 = x + (size_t)r1g * 256 + hi * 8;
#pragma unroll
      for (int kk = 0; kk < 8; ++kk) {
        const f32x4 u0 = *(const f32x4*)(p0 + kk * 32);
        const f32x4 u1 = *(const f32x4*)(p0 + kk * 32 + 4);
        const f32x4 v0 = *(const f32x4*)(p1 + kk * 32);
        const f32x4 v1 = *(const f32x4*)(p1 + kk * 32 + 4);
        A0[kk] = pack8(u0, u1);
        A1[kk] = pack8(v0, v1);
      }
    }

    // ---- score: cc-outer MFMA, B from LDS (conflict-free lane-linear) ----
    float s0v[4] = {0.f, 0.f, 0.f, 0.f};
    float s1v[4] = {0.f, 0.f, 0.f, 0.f};
#pragma unroll 2
    for (int cc = 0; cc < 16; ++cc) {
      KEEPA(A0);  // pin A in VGPRs across the loop
      KEEPA(A1);
      const char* bb = bwave + cc * 8192;
      f32x4 acc0 = {0.f, 0.f, 0.f, 0.f}, acc1 = {0.f, 0.f, 0.f, 0.f};
#pragma unroll
      for (int kk = 0; kk < 8; ++kk) {
        const bfrag_t Bk = *(const bfrag_t*)(bb + kk * 1024);
        acc0 = __builtin_amdgcn_mfma_f32_16x16x32_bf16(A0[kk], Bk, acc0, 0, 0, 0);
        acc1 = __builtin_amdgcn_mfma_f32_16x16x32_bf16(A1[kk], Bk, acc1, 0, 0, 0);
      }
      const float b1c = b1s[cc * 16 + l15];
      const float w2c = w2s[cc * 16 + l15];
#pragma unroll
      for (int r = 0; r < 4; ++r) {
        s0v[r] += tanh_fast(acc0[r] + b1c) * w2c;
        s1v[r] += tanh_fast(acc1[r] + b1c) * w2c;
      }
    }

    // ---- reduce over 16-lane col groups; w = exp(score + b2) ----
    f32x4 w0v, w1v;
#pragma unroll
    for (int r = 0; r < 4; ++r) {
      float v0 = s0v[r], v1 = s1v[r];
      v0 += __shfl_xor(v0, 1); v0 += __shfl_xor(v0, 2);
      v0 += __shfl_xor(v0, 4); v0 += __shfl_xor(v0, 8);
      v1 += __shfl_xor(v1, 1); v1 += __shfl_xor(v1, 2);
      v1 += __shfl_xor(v1, 4); v1 += __shfl_xor(v1, 8);
      w0v[r] = (R0 + hi * 4 + r < N) ? __expf(v0 + b2c) : 0.f;
      w1v[r] = (R0 + 16 + hi * 4 + r < N) ? __expf(v1 + b2c) : 0.f;
    }
    // Z partial: rows unique per (hi,r); reduce across hi
    {
      float z = w0v[0] + w0v[1] + w0v[2] + w0v[3] + w1v[0] + w1v[1] + w1v[2] + w1v[3];
      z += __shfl_xor(z, 16);
      z += __shfl_xor(z, 32);
      zacc += z;
    }

    // ---- broadcast w by row via per-wave LDS slice (no barrier: same wave) ----
    if (l15 == 0) {
      *(f32x4*)(ws + hi * 4) = w0v;        // rows hi*4+r
      *(f32x4*)(ws + 16 + hi * 4) = w1v;   // rows 16+hi*4+r
    }
    const float w0f = ws[l15];         // weight of row l15
    const float w1f = ws[l15 + 16];    // weight of row 16+l15

    // ---- segmented pooling straight from the bf16 registers ----
    const int g_first = __builtin_amdgcn_readlane(bid, 0);
    const int g_last  = __builtin_amdgcn_readlane(bid, 31);
    if (g_first == g_last) {
      if (g_first != gcur) { if (gcur >= 0) flush(); gcur = g_first; }
      pool_pass(w0f, w1f);
    } else {
      int s = 0;
      while (s < 32) {
        const int g = __builtin_amdgcn_readlane(bid, s);
        int e = s + 1;
        while (e < 32 && __builtin_amdgcn_readlane(bid, e) == g) ++e;
        if (g != gcur) { if (gcur >= 0) flush(); gcur = g; }
        const float m0 = (l15 >= s && l15 < e) ? w0f : 0.f;
        const float m1 = (16 + l15 >= s && 16 + l15 < e) ? w1f : 0.f;
        pool_pass(m0, m1);
        s = e;
      }
    }
  }

  if (gcur >= 0) flush();
  if (lane == 0 && zacc != 0.f) atomicAdd(Zp, zacc);
}

__global__ void finalize_kernel(float* __restrict__ out, const float* __restrict__ Zp, int n4) {
  const int i = blockIdx.x * blockDim.x + threadIdx.x;
  if (i < n4) {
    const float zi = 1.f / Zp[0];
    f32x4* p = (f32x4*)out;
    f32x4 v = p[i];
    v[0] *= zi; v[1] *= zi; v[2] *= zi; v[3] *= zi;
    p[i] = v;
  }
}

extern "C" void kernel_launch(void* const* d_in, const int* in_sizes, int n_in,
                              void* d_out, int out_size, void* d_ws, size_t ws_size,
                              hipStream_t stream) {
  const float* x  = (const float*)d_in[0];
  const int* batch = (const int*)d_in[1];
  const float* W1 = (const float*)d_in[2];
  const float* b1 = (const float*)d_in[3];
  const float* W2 = (const float*)d_in[4];
  const float* b2 = (const float*)d_in[5];
  float* out = (float*)d_out;
  const int N = in_sizes[1];

  unsigned short* W1f = (unsigned short*)d_ws;          // 128 KB
  float* Zp = (float*)((char*)d_ws + 131072);           // 4 B

  static int attr_done = 0;  // host-side only; idempotent attribute, not kernel state
  if (!attr_done) {
    hipFuncSetAttribute((const void*)attnpool_kernel,
                        hipFuncAttributeMaxDynamicSharedMemorySize, SMEM_BYTES);
    attr_done = 1;
  }

  const int ntiles = (N + 31) / 32;
  const int tps = (ntiles + SLOTS - 1) / SLOTS;

  hipMemsetAsync(d_out, 0, (size_t)out_size * sizeof(float), stream);
  hipMemsetAsync(Zp, 0, sizeof(float), stream);
  prep_w1_kernel<<<128, 64, 0, stream>>>(W1, W1f);
  attnpool_kernel<<<NBLOCKS, 1024, SMEM_BYTES, stream>>>(x, batch, W1f, b1, W2, b2,
                                                         out, Zp, N, ntiles, tps);
  finalize_kernel<<<(out_size / 4 + 255) / 256, 256, 0, stream>>>(out, Zp, out_size / 4);
}